// Round 1
// baseline (926.109 us; speedup 1.0000x reference)
//
#include <hip/hip_runtime.h>

#define DFEAT 128

// ---------------- CSR build ----------------

__global__ __launch_bounds__(256) void count_k(const int* __restrict__ dst, int* __restrict__ cnt, int E) {
    int i = blockIdx.x * 256 + threadIdx.x;
    if (i < E) atomicAdd(&cnt[dst[i]], 1);
}

__global__ __launch_bounds__(256) void dinv_k(const int* __restrict__ cnt, float* __restrict__ dinv, int n) {
    int i = blockIdx.x * 256 + threadIdx.x;
    if (i < n) dinv[i] = rsqrtf((float)(cnt[i] + 1));  // +1 self loop
}

// block-level exclusive scan: 1024 elements/block (256 thr x 4)
__global__ __launch_bounds__(256) void scan1_k(const int* __restrict__ cnt, int* __restrict__ excl,
                                               int* __restrict__ bsums, int n) {
    __shared__ int sd[256];
    int t = threadIdx.x;
    int base = blockIdx.x * 1024 + t * 4;
    int v0 = (base + 0 < n) ? cnt[base + 0] : 0;
    int v1 = (base + 1 < n) ? cnt[base + 1] : 0;
    int v2 = (base + 2 < n) ? cnt[base + 2] : 0;
    int v3 = (base + 3 < n) ? cnt[base + 3] : 0;
    int tsum = v0 + v1 + v2 + v3;
    sd[t] = tsum;
    __syncthreads();
    for (int off = 1; off < 256; off <<= 1) {
        int x = (t >= off) ? sd[t - off] : 0;
        __syncthreads();
        sd[t] += x;
        __syncthreads();
    }
    int incl = sd[t];
    int texcl = incl - tsum;
    if (t == 255) bsums[blockIdx.x] = incl;
    int run = texcl;
    if (base + 0 < n) excl[base + 0] = run; run += v0;
    if (base + 1 < n) excl[base + 1] = run; run += v1;
    if (base + 2 < n) excl[base + 2] = run; run += v2;
    if (base + 3 < n) excl[base + 3] = run;
}

__global__ __launch_bounds__(128) void scan2_k(const int* __restrict__ bsums, int* __restrict__ boffs, int nb) {
    __shared__ int sd[128];
    int t = threadIdx.x;
    int v = (t < nb) ? bsums[t] : 0;
    sd[t] = v;
    __syncthreads();
    for (int off = 1; off < 128; off <<= 1) {
        int x = (t >= off) ? sd[t - off] : 0;
        __syncthreads();
        sd[t] += x;
        __syncthreads();
    }
    boffs[t] = sd[t] - v;  // exclusive
}

__global__ __launch_bounds__(256) void scan3_k(int* __restrict__ rp, const int* __restrict__ boffs, int n, int total) {
    int i = blockIdx.x * 256 + threadIdx.x;
    if (i < n) rp[i] += boffs[i >> 10];
    if (i == 0) rp[n] = total;
}

__global__ __launch_bounds__(256) void scatter_k(const int* __restrict__ src, const int* __restrict__ dst,
                                                 const float* __restrict__ dinv, const int* __restrict__ rp,
                                                 int* __restrict__ fill, int* __restrict__ col,
                                                 float* __restrict__ wgt, int E) {
    int i = blockIdx.x * 256 + threadIdx.x;
    if (i >= E) return;
    int d = dst[i], s = src[i];
    int p = rp[d] + atomicAdd(&fill[d], 1);
    col[p] = s;
    wgt[p] = dinv[s] * dinv[d];
}

// ---------------- GEMM: C[n x 128] = A[n x 128] @ W[128 x 128] ----------------
// 64-row tile, BK=32, thread tile 4 rows x (4+4) cols, f32.

__global__ __launch_bounds__(256) void gemm_k(const float* __restrict__ A, const float* __restrict__ W,
                                              float* __restrict__ C, int n) {
    __shared__ float As[64][36];     // +4 pad keeps float4 alignment, breaks stride conflicts
    __shared__ float Ws[32][128];
    const int tid = threadIdx.x;
    const int row0 = blockIdx.x * 64;
    const int tx = tid & 15;   // 16 col groups
    const int ty = tid >> 4;   // 16 row groups of 4 rows
    float acc[4][8];
#pragma unroll
    for (int i = 0; i < 4; ++i)
#pragma unroll
        for (int j = 0; j < 8; ++j) acc[i][j] = 0.f;

    const int lr = tid >> 3;   // 0..31 (A-load row)
    const int lq = tid & 7;    // 0..7  (A-load float4 col)
    const int wr = tid >> 5;   // 0..7  (W-load row)
    const int wq = tid & 31;   // 0..31 (W-load float4 col)

    for (int k0 = 0; k0 < DFEAT; k0 += 32) {
#pragma unroll
        for (int p = 0; p < 2; ++p) {
            int r = lr + p * 32;
            int gr = row0 + r;
            float4 v = make_float4(0.f, 0.f, 0.f, 0.f);
            if (gr < n) v = *(const float4*)&A[(size_t)gr * DFEAT + k0 + lq * 4];
            *(float4*)&As[r][lq * 4] = v;
        }
#pragma unroll
        for (int p = 0; p < 4; ++p) {
            int r = wr + p * 8;
            *(float4*)&Ws[r][wq * 4] = *(const float4*)&W[(size_t)(k0 + r) * DFEAT + wq * 4];
        }
        __syncthreads();
#pragma unroll
        for (int k = 0; k < 32; ++k) {
            float a0 = As[ty * 4 + 0][k];
            float a1 = As[ty * 4 + 1][k];
            float a2 = As[ty * 4 + 2][k];
            float a3 = As[ty * 4 + 3][k];
            float4 w0 = *(const float4*)&Ws[k][tx * 4];        // cols tx*4..+3
            float4 w1 = *(const float4*)&Ws[k][64 + tx * 4];   // cols 64+tx*4..+3
            acc[0][0] += a0 * w0.x; acc[0][1] += a0 * w0.y; acc[0][2] += a0 * w0.z; acc[0][3] += a0 * w0.w;
            acc[0][4] += a0 * w1.x; acc[0][5] += a0 * w1.y; acc[0][6] += a0 * w1.z; acc[0][7] += a0 * w1.w;
            acc[1][0] += a1 * w0.x; acc[1][1] += a1 * w0.y; acc[1][2] += a1 * w0.z; acc[1][3] += a1 * w0.w;
            acc[1][4] += a1 * w1.x; acc[1][5] += a1 * w1.y; acc[1][6] += a1 * w1.z; acc[1][7] += a1 * w1.w;
            acc[2][0] += a2 * w0.x; acc[2][1] += a2 * w0.y; acc[2][2] += a2 * w0.z; acc[2][3] += a2 * w0.w;
            acc[2][4] += a2 * w1.x; acc[2][5] += a2 * w1.y; acc[2][6] += a2 * w1.z; acc[2][7] += a2 * w1.w;
            acc[3][0] += a3 * w0.x; acc[3][1] += a3 * w0.y; acc[3][2] += a3 * w0.z; acc[3][3] += a3 * w0.w;
            acc[3][4] += a3 * w1.x; acc[3][5] += a3 * w1.y; acc[3][6] += a3 * w1.z; acc[3][7] += a3 * w1.w;
        }
        __syncthreads();
    }
#pragma unroll
    for (int i = 0; i < 4; ++i) {
        int gr = row0 + ty * 4 + i;
        if (gr < n) {
            float4 o0 = make_float4(acc[i][0], acc[i][1], acc[i][2], acc[i][3]);
            float4 o1 = make_float4(acc[i][4], acc[i][5], acc[i][6], acc[i][7]);
            *(float4*)&C[(size_t)gr * DFEAT + tx * 4] = o0;
            *(float4*)&C[(size_t)gr * DFEAT + 64 + tx * 4] = o1;
        }
    }
}

// ---------------- aggregation: out[i] = dinv[i]^2 * T[i] + sum_e w_e * T[col_e] + b ----------------
// one wave (64 lanes) per node, float2 per lane (128 floats per row).

__global__ __launch_bounds__(256) void agg_k(const float* __restrict__ T, const float* __restrict__ dinv,
                                             const int* __restrict__ rowptr, const int* __restrict__ col,
                                             const float* __restrict__ wgt, const float* __restrict__ bias,
                                             float* __restrict__ out, int relu, int n) {
    int wid = (int)((blockIdx.x * (size_t)blockDim.x + threadIdx.x) >> 6);
    int lane = threadIdx.x & 63;
    if (wid >= n) return;
    int fb = lane * 2;
    float di = dinv[wid];
    float2 t0 = *(const float2*)(T + (size_t)wid * DFEAT + fb);
    float ax = di * di * t0.x;
    float ay = di * di * t0.y;
    int s = rowptr[wid], e = rowptr[wid + 1];
    for (int p = s; p < e; ++p) {
        int c = col[p];
        float w = wgt[p];
        float2 tv = *(const float2*)(T + (size_t)c * DFEAT + fb);
        ax += w * tv.x;
        ay += w * tv.y;
    }
    ax += bias[fb];
    ay += bias[fb + 1];
    if (relu) { ax = fmaxf(ax, 0.f); ay = fmaxf(ay, 0.f); }
    float2 o; o.x = ax; o.y = ay;
    *(float2*)(out + (size_t)wid * DFEAT + fb) = o;
}

// ---------------- launch ----------------

extern "C" void kernel_launch(void* const* d_in, const int* in_sizes, int n_in,
                              void* d_out, int out_size, void* d_ws, size_t ws_size,
                              hipStream_t stream) {
    const float* x  = (const float*)d_in[0];
    const int*   ei = (const int*)d_in[1];
    const float* W1 = (const float*)d_in[2];
    const float* b1 = (const float*)d_in[3];
    const float* W2 = (const float*)d_in[4];
    const float* b2 = (const float*)d_in[5];
    const float* W3 = (const float*)d_in[6];
    const float* b3 = (const float*)d_in[7];
    float* out = (float*)d_out;

    const int N = in_sizes[0] / DFEAT;
    const int E = in_sizes[1] / 2;
    const int* srcp = ei;
    const int* dstp = ei + E;

    size_t off = 0;
    auto alloc = [&](size_t bytes) -> void* {
        void* p = (char*)d_ws + off;
        off += (bytes + 255) & ~(size_t)255;
        return p;
    };
    int*   cnt   = (int*)alloc((size_t)N * 4);        // degree counts, reused as fill cursor
    int*   rp    = (int*)alloc((size_t)(N + 1) * 4);  // CSR row_ptr
    int*   bsums = (int*)alloc(1024);
    int*   boffs = (int*)alloc(1024);
    float* dinv  = (float*)alloc((size_t)N * 4);
    int*   col   = (int*)alloc((size_t)E * 4);
    float* wgt   = (float*)alloc((size_t)E * 4);
    float* bufA  = (float*)alloc((size_t)N * DFEAT * 4);
    float* bufB  = (float*)alloc((size_t)N * DFEAT * 4);

    // ---- CSR build (by dst) ----
    hipMemsetAsync(cnt, 0, (size_t)N * 4, stream);
    count_k<<<(E + 255) / 256, 256, 0, stream>>>(dstp, cnt, E);
    dinv_k<<<(N + 255) / 256, 256, 0, stream>>>(cnt, dinv, N);
    int NB = (N + 1023) / 1024;   // 98 for N=100000, must be <=128
    scan1_k<<<NB, 256, 0, stream>>>(cnt, rp, bsums, N);
    scan2_k<<<1, 128, 0, stream>>>(bsums, boffs, NB);
    scan3_k<<<(N + 255) / 256, 256, 0, stream>>>(rp, boffs, N, E);
    hipMemsetAsync(cnt, 0, (size_t)N * 4, stream);    // now the fill cursor
    scatter_k<<<(E + 255) / 256, 256, 0, stream>>>(srcp, dstp, dinv, rp, cnt, col, wgt, E);

    // ---- 3 GCN layers ----
    int gemmGrid = (N + 63) / 64;
    int aggGrid  = (int)(((size_t)N * 64 + 255) / 256);

    gemm_k<<<gemmGrid, 256, 0, stream>>>(x, W1, bufB, N);
    agg_k<<<aggGrid, 256, 0, stream>>>(bufB, dinv, rp, col, wgt, b1, bufA, 1, N);

    gemm_k<<<gemmGrid, 256, 0, stream>>>(bufA, W2, bufB, N);
    agg_k<<<aggGrid, 256, 0, stream>>>(bufB, dinv, rp, col, wgt, b2, bufA, 1, N);

    gemm_k<<<gemmGrid, 256, 0, stream>>>(bufA, W3, bufB, N);
    agg_k<<<aggGrid, 256, 0, stream>>>(bufB, dinv, rp, col, wgt, b3, out, 0, N);
}

// Round 2
// 645.657 us; speedup vs baseline: 1.4344x; 1.4344x over previous
//
#include <hip/hip_runtime.h>
#include <hip/hip_fp16.h>

#define DFEAT 128

// ---------------- CSR build ----------------

__global__ __launch_bounds__(256) void count_k(const int* __restrict__ dst, int* __restrict__ cnt, int E) {
    int i = (blockIdx.x * 256 + threadIdx.x) * 4;
    if (i + 3 < E) {
        int4 d = *(const int4*)&dst[i];
        atomicAdd(&cnt[d.x], 1);
        atomicAdd(&cnt[d.y], 1);
        atomicAdd(&cnt[d.z], 1);
        atomicAdd(&cnt[d.w], 1);
    } else {
        for (int j = i; j < E; ++j) atomicAdd(&cnt[dst[j]], 1);
    }
}

__global__ __launch_bounds__(256) void dinv_k(const int* __restrict__ cnt, float* __restrict__ dinv, int n) {
    int i = blockIdx.x * 256 + threadIdx.x;
    if (i < n) dinv[i] = rsqrtf((float)(cnt[i] + 1));  // +1 self loop
}

// block-level exclusive scan: 1024 elements/block (256 thr x 4)
__global__ __launch_bounds__(256) void scan1_k(const int* __restrict__ cnt, int* __restrict__ excl,
                                               int* __restrict__ bsums, int n) {
    __shared__ int sd[256];
    int t = threadIdx.x;
    int base = blockIdx.x * 1024 + t * 4;
    int v0 = (base + 0 < n) ? cnt[base + 0] : 0;
    int v1 = (base + 1 < n) ? cnt[base + 1] : 0;
    int v2 = (base + 2 < n) ? cnt[base + 2] : 0;
    int v3 = (base + 3 < n) ? cnt[base + 3] : 0;
    int tsum = v0 + v1 + v2 + v3;
    sd[t] = tsum;
    __syncthreads();
    for (int off = 1; off < 256; off <<= 1) {
        int x = (t >= off) ? sd[t - off] : 0;
        __syncthreads();
        sd[t] += x;
        __syncthreads();
    }
    int incl = sd[t];
    int texcl = incl - tsum;
    if (t == 255) bsums[blockIdx.x] = incl;
    int run = texcl;
    if (base + 0 < n) excl[base + 0] = run; run += v0;
    if (base + 1 < n) excl[base + 1] = run; run += v1;
    if (base + 2 < n) excl[base + 2] = run; run += v2;
    if (base + 3 < n) excl[base + 3] = run;
}

__global__ __launch_bounds__(128) void scan2_k(const int* __restrict__ bsums, int* __restrict__ boffs, int nb) {
    __shared__ int sd[128];
    int t = threadIdx.x;
    int v = (t < nb) ? bsums[t] : 0;
    sd[t] = v;
    __syncthreads();
    for (int off = 1; off < 128; off <<= 1) {
        int x = (t >= off) ? sd[t - off] : 0;
        __syncthreads();
        sd[t] += x;
        __syncthreads();
    }
    boffs[t] = sd[t] - v;  // exclusive
}

__global__ __launch_bounds__(256) void scan3_k(int* __restrict__ rp, const int* __restrict__ boffs, int n, int total) {
    int i = blockIdx.x * 256 + threadIdx.x;
    if (i < n) rp[i] += boffs[i >> 10];
    if (i == 0) rp[n] = total;
}

__global__ __launch_bounds__(256) void scatter_k(const int* __restrict__ src, const int* __restrict__ dst,
                                                 const float* __restrict__ dinv, const int* __restrict__ rp,
                                                 int* __restrict__ fill, int* __restrict__ col,
                                                 float* __restrict__ wgt, int E) {
    int i = blockIdx.x * 256 + threadIdx.x;
    if (i >= E) return;
    int d = dst[i], s = src[i];
    int p = rp[d] + atomicAdd(&fill[d], 1);
    col[p] = s;
    wgt[p] = dinv[s] * dinv[d];
}

// ---------------- GEMM: C[n x 128] = A[n x 128] @ W[128 x 128], C in f16 ----------------
// 64-row tile, BK=32, thread tile 4 rows x (4+4) cols, f32 accumulate, f16 store.

__global__ __launch_bounds__(256) void gemm_k(const float* __restrict__ A, const float* __restrict__ W,
                                              __half* __restrict__ C, int n) {
    __shared__ float As[64][36];     // row stride 36 floats = 144 B (16B-aligned), breaks conflicts
    __shared__ float Ws[32][128];
    const int tid = threadIdx.x;
    const int row0 = blockIdx.x * 64;
    const int tx = tid & 15;   // 16 col groups
    const int ty = tid >> 4;   // 16 row groups of 4 rows
    float acc[4][8];
#pragma unroll
    for (int i = 0; i < 4; ++i)
#pragma unroll
        for (int j = 0; j < 8; ++j) acc[i][j] = 0.f;

    const int lr = tid >> 3;   // 0..31 (A-load row)
    const int lq = tid & 7;    // 0..7  (A-load float4 col)
    const int wr = tid >> 5;   // 0..7  (W-load row)
    const int wq = tid & 31;   // 0..31 (W-load float4 col)

    for (int k0 = 0; k0 < DFEAT; k0 += 32) {
#pragma unroll
        for (int p = 0; p < 2; ++p) {
            int r = lr + p * 32;
            int gr = row0 + r;
            float4 v = make_float4(0.f, 0.f, 0.f, 0.f);
            if (gr < n) v = *(const float4*)&A[(size_t)gr * DFEAT + k0 + lq * 4];
            *(float4*)&As[r][lq * 4] = v;
        }
#pragma unroll
        for (int p = 0; p < 4; ++p) {
            int r = wr + p * 8;
            *(float4*)&Ws[r][wq * 4] = *(const float4*)&W[(size_t)(k0 + r) * DFEAT + wq * 4];
        }
        __syncthreads();
#pragma unroll
        for (int k = 0; k < 32; ++k) {
            float a0 = As[ty * 4 + 0][k];
            float a1 = As[ty * 4 + 1][k];
            float a2 = As[ty * 4 + 2][k];
            float a3 = As[ty * 4 + 3][k];
            float4 w0 = *(const float4*)&Ws[k][tx * 4];
            float4 w1 = *(const float4*)&Ws[k][64 + tx * 4];
            acc[0][0] += a0 * w0.x; acc[0][1] += a0 * w0.y; acc[0][2] += a0 * w0.z; acc[0][3] += a0 * w0.w;
            acc[0][4] += a0 * w1.x; acc[0][5] += a0 * w1.y; acc[0][6] += a0 * w1.z; acc[0][7] += a0 * w1.w;
            acc[1][0] += a1 * w0.x; acc[1][1] += a1 * w0.y; acc[1][2] += a1 * w0.z; acc[1][3] += a1 * w0.w;
            acc[1][4] += a1 * w1.x; acc[1][5] += a1 * w1.y; acc[1][6] += a1 * w1.z; acc[1][7] += a1 * w1.w;
            acc[2][0] += a2 * w0.x; acc[2][1] += a2 * w0.y; acc[2][2] += a2 * w0.z; acc[2][3] += a2 * w0.w;
            acc[2][4] += a2 * w1.x; acc[2][5] += a2 * w1.y; acc[2][6] += a2 * w1.z; acc[2][7] += a2 * w1.w;
            acc[3][0] += a3 * w0.x; acc[3][1] += a3 * w0.y; acc[3][2] += a3 * w0.z; acc[3][3] += a3 * w0.w;
            acc[3][4] += a3 * w1.x; acc[3][5] += a3 * w1.y; acc[3][6] += a3 * w1.z; acc[3][7] += a3 * w1.w;
        }
        __syncthreads();
    }
#pragma unroll
    for (int i = 0; i < 4; ++i) {
        int gr = row0 + ty * 4 + i;
        if (gr < n) {
            union { __half2 h[2]; float2 f; } u0, u1;
            u0.h[0] = __floats2half2_rn(acc[i][0], acc[i][1]);
            u0.h[1] = __floats2half2_rn(acc[i][2], acc[i][3]);
            u1.h[0] = __floats2half2_rn(acc[i][4], acc[i][5]);
            u1.h[1] = __floats2half2_rn(acc[i][6], acc[i][7]);
            *(float2*)&C[(size_t)gr * DFEAT + tx * 4] = u0.f;
            *(float2*)&C[(size_t)gr * DFEAT + 64 + tx * 4] = u1.f;
        }
    }
}

// ---------------- aggregation: out[i] = dinv[i]^2 * T[i] + sum_e w_e * T[col_e] + b ----------------
// one wave (64 lanes) per node; T is f16, each lane covers 2 features (half2 = 4 B).
// Edge loop unrolled x4: 4 independent gathers in flight per wave.

__global__ __launch_bounds__(256) void agg_k(const __half* __restrict__ T, const float* __restrict__ dinv,
                                             const int* __restrict__ rowptr, const int* __restrict__ col,
                                             const float* __restrict__ wgt, const float* __restrict__ bias,
                                             float* __restrict__ out, int relu, int n) {
    int wid = (int)((blockIdx.x * (size_t)blockDim.x + threadIdx.x) >> 6);
    int lane = threadIdx.x & 63;
    if (wid >= n) return;
    int fb = lane * 2;
    float di = dinv[wid];
    float2 t0 = __half22float2(*(const __half2*)(T + (size_t)wid * DFEAT + fb));
    float ax = di * di * t0.x;
    float ay = di * di * t0.y;
    int s = rowptr[wid], e = rowptr[wid + 1];
    int p = s;
    int e4 = s + ((e - s) & ~3);
    for (; p < e4; p += 4) {
        int c0 = col[p], c1 = col[p + 1], c2 = col[p + 2], c3 = col[p + 3];
        float w0 = wgt[p], w1 = wgt[p + 1], w2 = wgt[p + 2], w3 = wgt[p + 3];
        float2 v0 = __half22float2(*(const __half2*)(T + (size_t)c0 * DFEAT + fb));
        float2 v1 = __half22float2(*(const __half2*)(T + (size_t)c1 * DFEAT + fb));
        float2 v2 = __half22float2(*(const __half2*)(T + (size_t)c2 * DFEAT + fb));
        float2 v3 = __half22float2(*(const __half2*)(T + (size_t)c3 * DFEAT + fb));
        ax += w0 * v0.x; ay += w0 * v0.y;
        ax += w1 * v1.x; ay += w1 * v1.y;
        ax += w2 * v2.x; ay += w2 * v2.y;
        ax += w3 * v3.x; ay += w3 * v3.y;
    }
    for (; p < e; ++p) {
        int c = col[p];
        float w = wgt[p];
        float2 tv = __half22float2(*(const __half2*)(T + (size_t)c * DFEAT + fb));
        ax += w * tv.x;
        ay += w * tv.y;
    }
    ax += bias[fb];
    ay += bias[fb + 1];
    if (relu) { ax = fmaxf(ax, 0.f); ay = fmaxf(ay, 0.f); }
    float2 o; o.x = ax; o.y = ay;
    *(float2*)(out + (size_t)wid * DFEAT + fb) = o;
}

// ---------------- launch ----------------

extern "C" void kernel_launch(void* const* d_in, const int* in_sizes, int n_in,
                              void* d_out, int out_size, void* d_ws, size_t ws_size,
                              hipStream_t stream) {
    const float* x  = (const float*)d_in[0];
    const int*   ei = (const int*)d_in[1];
    const float* W1 = (const float*)d_in[2];
    const float* b1 = (const float*)d_in[3];
    const float* W2 = (const float*)d_in[4];
    const float* b2 = (const float*)d_in[5];
    const float* W3 = (const float*)d_in[6];
    const float* b3 = (const float*)d_in[7];
    float* out = (float*)d_out;

    const int N = in_sizes[0] / DFEAT;
    const int E = in_sizes[1] / 2;
    const int* srcp = ei;
    const int* dstp = ei + E;

    size_t off = 0;
    auto alloc = [&](size_t bytes) -> void* {
        void* p = (char*)d_ws + off;
        off += (bytes + 255) & ~(size_t)255;
        return p;
    };
    int*    cnt   = (int*)alloc((size_t)N * 4);        // degree counts, reused as fill cursor
    int*    rp    = (int*)alloc((size_t)(N + 1) * 4);  // CSR row_ptr
    int*    bsums = (int*)alloc(1024);
    int*    boffs = (int*)alloc(1024);
    float*  dinv  = (float*)alloc((size_t)N * 4);
    int*    col   = (int*)alloc((size_t)E * 4);
    float*  wgt   = (float*)alloc((size_t)E * 4);
    float*  bufA  = (float*)alloc((size_t)N * DFEAT * 4);   // agg output (f32, GEMM input)
    __half* bufT  = (__half*)alloc((size_t)N * DFEAT * 2);  // GEMM output (f16, gather src)

    // ---- CSR build (by dst) ----
    hipMemsetAsync(cnt, 0, (size_t)N * 4, stream);
    count_k<<<(E / 4 + 255) / 256, 256, 0, stream>>>(dstp, cnt, E);
    dinv_k<<<(N + 255) / 256, 256, 0, stream>>>(cnt, dinv, N);
    int NB = (N + 1023) / 1024;   // 98 for N=100000, must be <=128
    scan1_k<<<NB, 256, 0, stream>>>(cnt, rp, bsums, N);
    scan2_k<<<1, 128, 0, stream>>>(bsums, boffs, NB);
    scan3_k<<<(N + 255) / 256, 256, 0, stream>>>(rp, boffs, N, E);
    hipMemsetAsync(cnt, 0, (size_t)N * 4, stream);    // now the fill cursor
    scatter_k<<<(E + 255) / 256, 256, 0, stream>>>(srcp, dstp, dinv, rp, cnt, col, wgt, E);

    // ---- 3 GCN layers ----
    int gemmGrid = (N + 63) / 64;
    int aggGrid  = (int)(((size_t)N * 64 + 255) / 256);

    gemm_k<<<gemmGrid, 256, 0, stream>>>(x, W1, bufT, N);
    agg_k<<<aggGrid, 256, 0, stream>>>(bufT, dinv, rp, col, wgt, b1, bufA, 1, N);

    gemm_k<<<gemmGrid, 256, 0, stream>>>(bufA, W2, bufT, N);
    agg_k<<<aggGrid, 256, 0, stream>>>(bufT, dinv, rp, col, wgt, b2, bufA, 1, N);

    gemm_k<<<gemmGrid, 256, 0, stream>>>(bufA, W3, bufT, N);
    agg_k<<<aggGrid, 256, 0, stream>>>(bufT, dinv, rp, col, wgt, b3, out, 0, N);
}

// Round 3
// 603.201 us; speedup vs baseline: 1.5353x; 1.0704x over previous
//
#include <hip/hip_runtime.h>
#include <hip/hip_fp16.h>

#define DFEAT 128

// ---------------- CSR build ----------------

__global__ __launch_bounds__(256) void count_k(const int* __restrict__ dst, int* __restrict__ cnt, int E) {
    int i = (blockIdx.x * 256 + threadIdx.x) * 4;
    if (i + 3 < E) {
        int4 d = *(const int4*)&dst[i];
        atomicAdd(&cnt[d.x], 1);
        atomicAdd(&cnt[d.y], 1);
        atomicAdd(&cnt[d.z], 1);
        atomicAdd(&cnt[d.w], 1);
    } else {
        for (int j = i; j < E; ++j) atomicAdd(&cnt[dst[j]], 1);
    }
}

__global__ __launch_bounds__(256) void dinv_k(const int* __restrict__ cnt, float* __restrict__ dinv, int n) {
    int i = blockIdx.x * 256 + threadIdx.x;
    if (i < n) dinv[i] = rsqrtf((float)(cnt[i] + 1));  // +1 self loop
}

// block-level exclusive scan: 1024 elements/block (256 thr x 4)
__global__ __launch_bounds__(256) void scan1_k(const int* __restrict__ cnt, int* __restrict__ excl,
                                               int* __restrict__ bsums, int n) {
    __shared__ int sd[256];
    int t = threadIdx.x;
    int base = blockIdx.x * 1024 + t * 4;
    int v0 = (base + 0 < n) ? cnt[base + 0] : 0;
    int v1 = (base + 1 < n) ? cnt[base + 1] : 0;
    int v2 = (base + 2 < n) ? cnt[base + 2] : 0;
    int v3 = (base + 3 < n) ? cnt[base + 3] : 0;
    int tsum = v0 + v1 + v2 + v3;
    sd[t] = tsum;
    __syncthreads();
    for (int off = 1; off < 256; off <<= 1) {
        int x = (t >= off) ? sd[t - off] : 0;
        __syncthreads();
        sd[t] += x;
        __syncthreads();
    }
    int incl = sd[t];
    int texcl = incl - tsum;
    if (t == 255) bsums[blockIdx.x] = incl;
    int run = texcl;
    if (base + 0 < n) excl[base + 0] = run; run += v0;
    if (base + 1 < n) excl[base + 1] = run; run += v1;
    if (base + 2 < n) excl[base + 2] = run; run += v2;
    if (base + 3 < n) excl[base + 3] = run;
}

__global__ __launch_bounds__(128) void scan2_k(const int* __restrict__ bsums, int* __restrict__ boffs, int nb) {
    __shared__ int sd[128];
    int t = threadIdx.x;
    int v = (t < nb) ? bsums[t] : 0;
    sd[t] = v;
    __syncthreads();
    for (int off = 1; off < 128; off <<= 1) {
        int x = (t >= off) ? sd[t - off] : 0;
        __syncthreads();
        sd[t] += x;
        __syncthreads();
    }
    boffs[t] = sd[t] - v;  // exclusive
}

__global__ __launch_bounds__(256) void scan3_k(int* __restrict__ rp, const int* __restrict__ boffs, int n, int total) {
    int i = blockIdx.x * 256 + threadIdx.x;
    if (i < n) rp[i] += boffs[i >> 10];
    if (i == 0) rp[n] = total;
}

// one 8B store per edge: {col, wgt} interleaved -> one dirty line per edge, not two
__global__ __launch_bounds__(256) void scatter_k(const int* __restrict__ src, const int* __restrict__ dst,
                                                 const float* __restrict__ dinv, const int* __restrict__ rp,
                                                 int* __restrict__ fill, int2* __restrict__ cw, int E) {
    int i = blockIdx.x * 256 + threadIdx.x;
    if (i >= E) return;
    int d = dst[i], s = src[i];
    int p = rp[d] + atomicAdd(&fill[d], 1);
    float w = dinv[s] * dinv[d];
    int2 rec;
    rec.x = s;
    rec.y = __float_as_int(w);
    cw[p] = rec;
}

// ---------------- GEMM: C[n x 128] = A[n x 128] @ W[128 x 128], C in f16 ----------------
// 64-row tile, BK=32, thread tile 4 rows x (4+4) cols, f32 accumulate, f16 store.

__global__ __launch_bounds__(256) void gemm_k(const float* __restrict__ A, const float* __restrict__ W,
                                              __half* __restrict__ C, int n) {
    __shared__ float As[64][36];     // row stride 36 floats = 144 B (16B-aligned), breaks conflicts
    __shared__ float Ws[32][128];
    const int tid = threadIdx.x;
    const int row0 = blockIdx.x * 64;
    const int tx = tid & 15;   // 16 col groups
    const int ty = tid >> 4;   // 16 row groups of 4 rows
    float acc[4][8];
#pragma unroll
    for (int i = 0; i < 4; ++i)
#pragma unroll
        for (int j = 0; j < 8; ++j) acc[i][j] = 0.f;

    const int lr = tid >> 3;   // 0..31 (A-load row)
    const int lq = tid & 7;    // 0..7  (A-load float4 col)
    const int wr = tid >> 5;   // 0..7  (W-load row)
    const int wq = tid & 31;   // 0..31 (W-load float4 col)

    for (int k0 = 0; k0 < DFEAT; k0 += 32) {
#pragma unroll
        for (int p = 0; p < 2; ++p) {
            int r = lr + p * 32;
            int gr = row0 + r;
            float4 v = make_float4(0.f, 0.f, 0.f, 0.f);
            if (gr < n) v = *(const float4*)&A[(size_t)gr * DFEAT + k0 + lq * 4];
            *(float4*)&As[r][lq * 4] = v;
        }
#pragma unroll
        for (int p = 0; p < 4; ++p) {
            int r = wr + p * 8;
            *(float4*)&Ws[r][wq * 4] = *(const float4*)&W[(size_t)(k0 + r) * DFEAT + wq * 4];
        }
        __syncthreads();
#pragma unroll
        for (int k = 0; k < 32; ++k) {
            float a0 = As[ty * 4 + 0][k];
            float a1 = As[ty * 4 + 1][k];
            float a2 = As[ty * 4 + 2][k];
            float a3 = As[ty * 4 + 3][k];
            float4 w0 = *(const float4*)&Ws[k][tx * 4];
            float4 w1 = *(const float4*)&Ws[k][64 + tx * 4];
            acc[0][0] += a0 * w0.x; acc[0][1] += a0 * w0.y; acc[0][2] += a0 * w0.z; acc[0][3] += a0 * w0.w;
            acc[0][4] += a0 * w1.x; acc[0][5] += a0 * w1.y; acc[0][6] += a0 * w1.z; acc[0][7] += a0 * w1.w;
            acc[1][0] += a1 * w0.x; acc[1][1] += a1 * w0.y; acc[1][2] += a1 * w0.z; acc[1][3] += a1 * w0.w;
            acc[1][4] += a1 * w1.x; acc[1][5] += a1 * w1.y; acc[1][6] += a1 * w1.z; acc[1][7] += a1 * w1.w;
            acc[2][0] += a2 * w0.x; acc[2][1] += a2 * w0.y; acc[2][2] += a2 * w0.z; acc[2][3] += a2 * w0.w;
            acc[2][4] += a2 * w1.x; acc[2][5] += a2 * w1.y; acc[2][6] += a2 * w1.z; acc[2][7] += a2 * w1.w;
            acc[3][0] += a3 * w0.x; acc[3][1] += a3 * w0.y; acc[3][2] += a3 * w0.z; acc[3][3] += a3 * w0.w;
            acc[3][4] += a3 * w1.x; acc[3][5] += a3 * w1.y; acc[3][6] += a3 * w1.z; acc[3][7] += a3 * w1.w;
        }
        __syncthreads();
    }
#pragma unroll
    for (int i = 0; i < 4; ++i) {
        int gr = row0 + ty * 4 + i;
        if (gr < n) {
            union { __half2 h[2]; float2 f; } u0, u1;
            u0.h[0] = __floats2half2_rn(acc[i][0], acc[i][1]);
            u0.h[1] = __floats2half2_rn(acc[i][2], acc[i][3]);
            u1.h[0] = __floats2half2_rn(acc[i][4], acc[i][5]);
            u1.h[1] = __floats2half2_rn(acc[i][6], acc[i][7]);
            *(float2*)&C[(size_t)gr * DFEAT + tx * 4] = u0.f;
            *(float2*)&C[(size_t)gr * DFEAT + 64 + tx * 4] = u1.f;
        }
    }
}

// ---------------- aggregation: out[i] = dinv[i]^2 * T[i] + sum_e w_e * T[col_e] + b ----------------
// one wave (64 lanes) per node; T is f16, each lane covers 2 features (half2 = 4 B).
// Edge loop unrolled x8: 8 independent gathers in flight per wave.

__global__ __launch_bounds__(256) void agg_k(const __half* __restrict__ T, const float* __restrict__ dinv,
                                             const int* __restrict__ rowptr, const int2* __restrict__ cw,
                                             const float* __restrict__ bias,
                                             float* __restrict__ out, int relu, int n) {
    int wid = (int)((blockIdx.x * (size_t)blockDim.x + threadIdx.x) >> 6);
    int lane = threadIdx.x & 63;
    if (wid >= n) return;
    int fb = lane * 2;
    float di = dinv[wid];
    float2 t0 = __half22float2(*(const __half2*)(T + (size_t)wid * DFEAT + fb));
    float ax = di * di * t0.x;
    float ay = di * di * t0.y;
    int s = rowptr[wid], e = rowptr[wid + 1];
    int p = s;
    int e8 = s + ((e - s) & ~7);
    for (; p < e8; p += 8) {
        int2 r0 = cw[p], r1 = cw[p + 1], r2 = cw[p + 2], r3 = cw[p + 3];
        int2 r4 = cw[p + 4], r5 = cw[p + 5], r6 = cw[p + 6], r7 = cw[p + 7];
        float2 v0 = __half22float2(*(const __half2*)(T + (size_t)r0.x * DFEAT + fb));
        float2 v1 = __half22float2(*(const __half2*)(T + (size_t)r1.x * DFEAT + fb));
        float2 v2 = __half22float2(*(const __half2*)(T + (size_t)r2.x * DFEAT + fb));
        float2 v3 = __half22float2(*(const __half2*)(T + (size_t)r3.x * DFEAT + fb));
        float2 v4 = __half22float2(*(const __half2*)(T + (size_t)r4.x * DFEAT + fb));
        float2 v5 = __half22float2(*(const __half2*)(T + (size_t)r5.x * DFEAT + fb));
        float2 v6 = __half22float2(*(const __half2*)(T + (size_t)r6.x * DFEAT + fb));
        float2 v7 = __half22float2(*(const __half2*)(T + (size_t)r7.x * DFEAT + fb));
        float w0 = __int_as_float(r0.y), w1 = __int_as_float(r1.y);
        float w2 = __int_as_float(r2.y), w3 = __int_as_float(r3.y);
        float w4 = __int_as_float(r4.y), w5 = __int_as_float(r5.y);
        float w6 = __int_as_float(r6.y), w7 = __int_as_float(r7.y);
        ax += w0 * v0.x; ay += w0 * v0.y;
        ax += w1 * v1.x; ay += w1 * v1.y;
        ax += w2 * v2.x; ay += w2 * v2.y;
        ax += w3 * v3.x; ay += w3 * v3.y;
        ax += w4 * v4.x; ay += w4 * v4.y;
        ax += w5 * v5.x; ay += w5 * v5.y;
        ax += w6 * v6.x; ay += w6 * v6.y;
        ax += w7 * v7.x; ay += w7 * v7.y;
    }
    int e4 = s + ((e - s) & ~3);
    if (p < e4) {
        int2 r0 = cw[p], r1 = cw[p + 1], r2 = cw[p + 2], r3 = cw[p + 3];
        float2 v0 = __half22float2(*(const __half2*)(T + (size_t)r0.x * DFEAT + fb));
        float2 v1 = __half22float2(*(const __half2*)(T + (size_t)r1.x * DFEAT + fb));
        float2 v2 = __half22float2(*(const __half2*)(T + (size_t)r2.x * DFEAT + fb));
        float2 v3 = __half22float2(*(const __half2*)(T + (size_t)r3.x * DFEAT + fb));
        float w0 = __int_as_float(r0.y), w1 = __int_as_float(r1.y);
        float w2 = __int_as_float(r2.y), w3 = __int_as_float(r3.y);
        ax += w0 * v0.x; ay += w0 * v0.y;
        ax += w1 * v1.x; ay += w1 * v1.y;
        ax += w2 * v2.x; ay += w2 * v2.y;
        ax += w3 * v3.x; ay += w3 * v3.y;
        p += 4;
    }
    for (; p < e; ++p) {
        int2 r = cw[p];
        float w = __int_as_float(r.y);
        float2 tv = __half22float2(*(const __half2*)(T + (size_t)r.x * DFEAT + fb));
        ax += w * tv.x;
        ay += w * tv.y;
    }
    ax += bias[fb];
    ay += bias[fb + 1];
    if (relu) { ax = fmaxf(ax, 0.f); ay = fmaxf(ay, 0.f); }
    float2 o; o.x = ax; o.y = ay;
    *(float2*)(out + (size_t)wid * DFEAT + fb) = o;
}

// ---------------- launch ----------------

extern "C" void kernel_launch(void* const* d_in, const int* in_sizes, int n_in,
                              void* d_out, int out_size, void* d_ws, size_t ws_size,
                              hipStream_t stream) {
    const float* x  = (const float*)d_in[0];
    const int*   ei = (const int*)d_in[1];
    const float* W1 = (const float*)d_in[2];
    const float* b1 = (const float*)d_in[3];
    const float* W2 = (const float*)d_in[4];
    const float* b2 = (const float*)d_in[5];
    const float* W3 = (const float*)d_in[6];
    const float* b3 = (const float*)d_in[7];
    float* out = (float*)d_out;

    const int N = in_sizes[0] / DFEAT;
    const int E = in_sizes[1] / 2;
    const int* srcp = ei;
    const int* dstp = ei + E;

    size_t off = 0;
    auto alloc = [&](size_t bytes) -> void* {
        void* p = (char*)d_ws + off;
        off += (bytes + 255) & ~(size_t)255;
        return p;
    };
    int*    cnt   = (int*)alloc((size_t)N * 4);        // degree counts, reused as fill cursor
    int*    rp    = (int*)alloc((size_t)(N + 1) * 4);  // CSR row_ptr
    int*    bsums = (int*)alloc(1024);
    int*    boffs = (int*)alloc(1024);
    float*  dinv  = (float*)alloc((size_t)N * 4);
    int2*   cw    = (int2*)alloc((size_t)E * 8);       // interleaved {col, wgt}
    float*  bufA  = (float*)alloc((size_t)N * DFEAT * 4);   // agg output (f32, GEMM input)
    __half* bufT  = (__half*)alloc((size_t)N * DFEAT * 2);  // GEMM output (f16, gather src)

    // ---- CSR build (by dst) ----
    hipMemsetAsync(cnt, 0, (size_t)N * 4, stream);
    count_k<<<(E / 4 + 255) / 256, 256, 0, stream>>>(dstp, cnt, E);
    dinv_k<<<(N + 255) / 256, 256, 0, stream>>>(cnt, dinv, N);
    int NB = (N + 1023) / 1024;   // 98 for N=100000, must be <=128
    scan1_k<<<NB, 256, 0, stream>>>(cnt, rp, bsums, N);
    scan2_k<<<1, 128, 0, stream>>>(bsums, boffs, NB);
    scan3_k<<<(N + 255) / 256, 256, 0, stream>>>(rp, boffs, N, E);
    hipMemsetAsync(cnt, 0, (size_t)N * 4, stream);    // now the fill cursor
    scatter_k<<<(E + 255) / 256, 256, 0, stream>>>(srcp, dstp, dinv, rp, cnt, cw, E);

    // ---- 3 GCN layers ----
    int gemmGrid = (N + 63) / 64;
    int aggGrid  = (int)(((size_t)N * 64 + 255) / 256);

    gemm_k<<<gemmGrid, 256, 0, stream>>>(x, W1, bufT, N);
    agg_k<<<aggGrid, 256, 0, stream>>>(bufT, dinv, rp, cw, b1, bufA, 1, N);

    gemm_k<<<gemmGrid, 256, 0, stream>>>(bufA, W2, bufT, N);
    agg_k<<<aggGrid, 256, 0, stream>>>(bufT, dinv, rp, cw, b2, bufA, 1, N);

    gemm_k<<<gemmGrid, 256, 0, stream>>>(bufA, W3, bufT, N);
    agg_k<<<aggGrid, 256, 0, stream>>>(bufT, dinv, rp, cw, b3, out, 0, N);
}

// Round 7
// 592.376 us; speedup vs baseline: 1.5634x; 1.0183x over previous
//
#include <hip/hip_runtime.h>
#include <hip/hip_fp16.h>

#define DFEAT 128

// ---------------- CSR build ----------------

__global__ __launch_bounds__(256) void count_k(const int* __restrict__ dst, int* __restrict__ cnt, int E) {
    int i = (blockIdx.x * 256 + threadIdx.x) * 4;
    if (i + 3 < E) {
        int4 d = *(const int4*)&dst[i];
        atomicAdd(&cnt[d.x], 1);
        atomicAdd(&cnt[d.y], 1);
        atomicAdd(&cnt[d.z], 1);
        atomicAdd(&cnt[d.w], 1);
    } else {
        for (int j = i; j < E; ++j) atomicAdd(&cnt[dst[j]], 1);
    }
}

__global__ __launch_bounds__(256) void dinv_k(const int* __restrict__ cnt, float* __restrict__ dinv, int n) {
    int i = blockIdx.x * 256 + threadIdx.x;
    if (i < n) dinv[i] = rsqrtf((float)(cnt[i] + 1));  // +1 self loop
}

// block-level exclusive scan: 1024 elements/block (256 thr x 4)
__global__ __launch_bounds__(256) void scan1_k(const int* __restrict__ cnt, int* __restrict__ excl,
                                               int* __restrict__ bsums, int n) {
    __shared__ int sd[256];
    int t = threadIdx.x;
    int base = blockIdx.x * 1024 + t * 4;
    int v0 = (base + 0 < n) ? cnt[base + 0] : 0;
    int v1 = (base + 1 < n) ? cnt[base + 1] : 0;
    int v2 = (base + 2 < n) ? cnt[base + 2] : 0;
    int v3 = (base + 3 < n) ? cnt[base + 3] : 0;
    int tsum = v0 + v1 + v2 + v3;
    sd[t] = tsum;
    __syncthreads();
    for (int off = 1; off < 256; off <<= 1) {
        int x = (t >= off) ? sd[t - off] : 0;
        __syncthreads();
        sd[t] += x;
        __syncthreads();
    }
    int incl = sd[t];
    int texcl = incl - tsum;
    if (t == 255) bsums[blockIdx.x] = incl;
    int run = texcl;
    if (base + 0 < n) excl[base + 0] = run; run += v0;
    if (base + 1 < n) excl[base + 1] = run; run += v1;
    if (base + 2 < n) excl[base + 2] = run; run += v2;
    if (base + 3 < n) excl[base + 3] = run;
}

__global__ __launch_bounds__(128) void scan2_k(const int* __restrict__ bsums, int* __restrict__ boffs, int nb) {
    __shared__ int sd[128];
    int t = threadIdx.x;
    int v = (t < nb) ? bsums[t] : 0;
    sd[t] = v;
    __syncthreads();
    for (int off = 1; off < 128; off <<= 1) {
        int x = (t >= off) ? sd[t - off] : 0;
        __syncthreads();
        sd[t] += x;
        __syncthreads();
    }
    boffs[t] = sd[t] - v;  // exclusive
}

__global__ __launch_bounds__(256) void scan3_k(int* __restrict__ rp, const int* __restrict__ boffs, int n, int total) {
    int i = blockIdx.x * 256 + threadIdx.x;
    if (i < n) rp[i] += boffs[i >> 10];
    if (i == 0) rp[n] = total;
}

// one 8B store per edge: {col, wgt} interleaved -> one dirty line per edge, not two
__global__ __launch_bounds__(256) void scatter_k(const int* __restrict__ src, const int* __restrict__ dst,
                                                 const float* __restrict__ dinv, const int* __restrict__ rp,
                                                 int* __restrict__ fill, int2* __restrict__ cw, int E) {
    int i = blockIdx.x * 256 + threadIdx.x;
    if (i >= E) return;
    int d = dst[i], s = src[i];
    int p = rp[d] + atomicAdd(&fill[d], 1);
    float w = dinv[s] * dinv[d];
    int2 rec;
    rec.x = s;
    rec.y = __float_as_int(w);
    cw[p] = rec;
}

// ---------------- GEMM: C[n x 128] = A[n x 128] @ W[128 x 128], C in f16 ----------------
// 64-row tile, BK=32, thread tile 4 rows x (4+4) cols, f32 accumulate, f16 store.

__global__ __launch_bounds__(256) void gemm_k(const float* __restrict__ A, const float* __restrict__ W,
                                              __half* __restrict__ C, int n) {
    __shared__ float As[64][36];     // row stride 36 floats = 144 B (16B-aligned), breaks conflicts
    __shared__ float Ws[32][128];
    const int tid = threadIdx.x;
    const int row0 = blockIdx.x * 64;
    const int tx = tid & 15;   // 16 col groups
    const int ty = tid >> 4;   // 16 row groups of 4 rows
    float acc[4][8];
#pragma unroll
    for (int i = 0; i < 4; ++i)
#pragma unroll
        for (int j = 0; j < 8; ++j) acc[i][j] = 0.f;

    const int lr = tid >> 3;   // 0..31 (A-load row)
    const int lq = tid & 7;    // 0..7  (A-load float4 col)
    const int wr = tid >> 5;   // 0..7  (W-load row)
    const int wq = tid & 31;   // 0..31 (W-load float4 col)

    for (int k0 = 0; k0 < DFEAT; k0 += 32) {
#pragma unroll
        for (int p = 0; p < 2; ++p) {
            int r = lr + p * 32;
            int gr = row0 + r;
            float4 v = make_float4(0.f, 0.f, 0.f, 0.f);
            if (gr < n) v = *(const float4*)&A[(size_t)gr * DFEAT + k0 + lq * 4];
            *(float4*)&As[r][lq * 4] = v;
        }
#pragma unroll
        for (int p = 0; p < 4; ++p) {
            int r = wr + p * 8;
            *(float4*)&Ws[r][wq * 4] = *(const float4*)&W[(size_t)(k0 + r) * DFEAT + wq * 4];
        }
        __syncthreads();
#pragma unroll
        for (int k = 0; k < 32; ++k) {
            float a0 = As[ty * 4 + 0][k];
            float a1 = As[ty * 4 + 1][k];
            float a2 = As[ty * 4 + 2][k];
            float a3 = As[ty * 4 + 3][k];
            float4 w0 = *(const float4*)&Ws[k][tx * 4];
            float4 w1 = *(const float4*)&Ws[k][64 + tx * 4];
            acc[0][0] += a0 * w0.x; acc[0][1] += a0 * w0.y; acc[0][2] += a0 * w0.z; acc[0][3] += a0 * w0.w;
            acc[0][4] += a0 * w1.x; acc[0][5] += a0 * w1.y; acc[0][6] += a0 * w1.z; acc[0][7] += a0 * w1.w;
            acc[1][0] += a1 * w0.x; acc[1][1] += a1 * w0.y; acc[1][2] += a1 * w0.z; acc[1][3] += a1 * w0.w;
            acc[1][4] += a1 * w1.x; acc[1][5] += a1 * w1.y; acc[1][6] += a1 * w1.z; acc[1][7] += a1 * w1.w;
            acc[2][0] += a2 * w0.x; acc[2][1] += a2 * w0.y; acc[2][2] += a2 * w0.z; acc[2][3] += a2 * w0.w;
            acc[2][4] += a2 * w1.x; acc[2][5] += a2 * w1.y; acc[2][6] += a2 * w1.z; acc[2][7] += a2 * w1.w;
            acc[3][0] += a3 * w0.x; acc[3][1] += a3 * w0.y; acc[3][2] += a3 * w0.z; acc[3][3] += a3 * w0.w;
            acc[3][4] += a3 * w1.x; acc[3][5] += a3 * w1.y; acc[3][6] += a3 * w1.z; acc[3][7] += a3 * w1.w;
        }
        __syncthreads();
    }
#pragma unroll
    for (int i = 0; i < 4; ++i) {
        int gr = row0 + ty * 4 + i;
        if (gr < n) {
            union { __half2 h[2]; float2 f; } u0, u1;
            u0.h[0] = __floats2half2_rn(acc[i][0], acc[i][1]);
            u0.h[1] = __floats2half2_rn(acc[i][2], acc[i][3]);
            u1.h[0] = __floats2half2_rn(acc[i][4], acc[i][5]);
            u1.h[1] = __floats2half2_rn(acc[i][6], acc[i][7]);
            *(float2*)&C[(size_t)gr * DFEAT + tx * 4] = u0.f;
            *(float2*)&C[(size_t)gr * DFEAT + 64 + tx * 4] = u1.f;
        }
    }
}

// ---------------- aggregation: out[i] = dinv[i]^2 * T[i] + sum_e w_e * T[col_e] + b ----------------
// one wave (64 lanes) per node; T is f16, each lane covers 2 features (half2 = 4 B).
// Edge loop unrolled x8: 8 independent gathers in flight per wave.

__global__ __launch_bounds__(256) void agg_k(const __half* __restrict__ T, const float* __restrict__ dinv,
                                             const int* __restrict__ rowptr, const int2* __restrict__ cw,
                                             const float* __restrict__ bias,
                                             float* __restrict__ out, int relu, int n) {
    int wid = (int)((blockIdx.x * (size_t)blockDim.x + threadIdx.x) >> 6);
    int lane = threadIdx.x & 63;
    if (wid >= n) return;
    int fb = lane * 2;
    float di = dinv[wid];
    float2 t0 = __half22float2(*(const __half2*)(T + (size_t)wid * DFEAT + fb));
    float ax = di * di * t0.x;
    float ay = di * di * t0.y;
    int s = rowptr[wid], e = rowptr[wid + 1];
    int p = s;
    int e8 = s + ((e - s) & ~7);
    for (; p < e8; p += 8) {
        int2 r0 = cw[p], r1 = cw[p + 1], r2 = cw[p + 2], r3 = cw[p + 3];
        int2 r4 = cw[p + 4], r5 = cw[p + 5], r6 = cw[p + 6], r7 = cw[p + 7];
        float2 v0 = __half22float2(*(const __half2*)(T + (size_t)r0.x * DFEAT + fb));
        float2 v1 = __half22float2(*(const __half2*)(T + (size_t)r1.x * DFEAT + fb));
        float2 v2 = __half22float2(*(const __half2*)(T + (size_t)r2.x * DFEAT + fb));
        float2 v3 = __half22float2(*(const __half2*)(T + (size_t)r3.x * DFEAT + fb));
        float2 v4 = __half22float2(*(const __half2*)(T + (size_t)r4.x * DFEAT + fb));
        float2 v5 = __half22float2(*(const __half2*)(T + (size_t)r5.x * DFEAT + fb));
        float2 v6 = __half22float2(*(const __half2*)(T + (size_t)r6.x * DFEAT + fb));
        float2 v7 = __half22float2(*(const __half2*)(T + (size_t)r7.x * DFEAT + fb));
        float w0 = __int_as_float(r0.y), w1 = __int_as_float(r1.y);
        float w2 = __int_as_float(r2.y), w3 = __int_as_float(r3.y);
        float w4 = __int_as_float(r4.y), w5 = __int_as_float(r5.y);
        float w6 = __int_as_float(r6.y), w7 = __int_as_float(r7.y);
        ax += w0 * v0.x; ay += w0 * v0.y;
        ax += w1 * v1.x; ay += w1 * v1.y;
        ax += w2 * v2.x; ay += w2 * v2.y;
        ax += w3 * v3.x; ay += w3 * v3.y;
        ax += w4 * v4.x; ay += w4 * v4.y;
        ax += w5 * v5.x; ay += w5 * v5.y;
        ax += w6 * v6.x; ay += w6 * v6.y;
        ax += w7 * v7.x; ay += w7 * v7.y;
    }
    int e4 = s + ((e - s) & ~3);
    if (p < e4) {
        int2 r0 = cw[p], r1 = cw[p + 1], r2 = cw[p + 2], r3 = cw[p + 3];
        float2 v0 = __half22float2(*(const __half2*)(T + (size_t)r0.x * DFEAT + fb));
        float2 v1 = __half22float2(*(const __half2*)(T + (size_t)r1.x * DFEAT + fb));
        float2 v2 = __half22float2(*(const __half2*)(T + (size_t)r2.x * DFEAT + fb));
        float2 v3 = __half22float2(*(const __half2*)(T + (size_t)r3.x * DFEAT + fb));
        float w0 = __int_as_float(r0.y), w1 = __int_as_float(r1.y);
        float w2 = __int_as_float(r2.y), w3 = __int_as_float(r3.y);
        ax += w0 * v0.x; ay += w0 * v0.y;
        ax += w1 * v1.x; ay += w1 * v1.y;
        ax += w2 * v2.x; ay += w2 * v2.y;
        ax += w3 * v3.x; ay += w3 * v3.y;
        p += 4;
    }
    for (; p < e; ++p) {
        int2 r = cw[p];
        float w = __int_as_float(r.y);
        float2 tv = __half22float2(*(const __half2*)(T + (size_t)r.x * DFEAT + fb));
        ax += w * tv.x;
        ay += w * tv.y;
    }
    ax += bias[fb];
    ay += bias[fb + 1];
    if (relu) { ax = fmaxf(ax, 0.f); ay = fmaxf(ay, 0.f); }
    float2 o; o.x = ax; o.y = ay;
    *(float2*)(out + (size_t)wid * DFEAT + fb) = o;
}

// ---------------- launch ----------------

extern "C" void kernel_launch(void* const* d_in, const int* in_sizes, int n_in,
                              void* d_out, int out_size, void* d_ws, size_t ws_size,
                              hipStream_t stream) {
    const float* x  = (const float*)d_in[0];
    const int*   ei = (const int*)d_in[1];
    const float* W1 = (const float*)d_in[2];
    const float* b1 = (const float*)d_in[3];
    const float* W2 = (const float*)d_in[4];
    const float* b2 = (const float*)d_in[5];
    const float* W3 = (const float*)d_in[6];
    const float* b3 = (const float*)d_in[7];
    float* out = (float*)d_out;

    const int N = in_sizes[0] / DFEAT;
    const int E = in_sizes[1] / 2;
    const int* srcp = ei;
    const int* dstp = ei + E;

    size_t off = 0;
    auto alloc = [&](size_t bytes) -> void* {
        void* p = (char*)d_ws + off;
        off += (bytes + 255) & ~(size_t)255;
        return p;
    };
    int*    cnt   = (int*)alloc((size_t)N * 4);        // degree counts, reused as fill cursor
    int*    rp    = (int*)alloc((size_t)(N + 1) * 4);  // CSR row_ptr
    int*    bsums = (int*)alloc(1024);
    int*    boffs = (int*)alloc(1024);
    float*  dinv  = (float*)alloc((size_t)N * 4);
    int2*   cw    = (int2*)alloc((size_t)E * 8);       // interleaved {col, wgt}
    float*  bufA  = (float*)alloc((size_t)N * DFEAT * 4);   // agg output (f32, GEMM input)
    __half* bufT  = (__half*)alloc((size_t)N * DFEAT * 2);  // GEMM output (f16, gather src)

    // ---- CSR build (by dst) ----
    hipMemsetAsync(cnt, 0, (size_t)N * 4, stream);
    count_k<<<(E / 4 + 255) / 256, 256, 0, stream>>>(dstp, cnt, E);
    dinv_k<<<(N + 255) / 256, 256, 0, stream>>>(cnt, dinv, N);
    int NB = (N + 1023) / 1024;   // 98 for N=100000, must be <=128
    scan1_k<<<NB, 256, 0, stream>>>(cnt, rp, bsums, N);
    scan2_k<<<1, 128, 0, stream>>>(bsums, boffs, NB);
    scan3_k<<<(N + 255) / 256, 256, 0, stream>>>(rp, boffs, N, E);
    hipMemsetAsync(cnt, 0, (size_t)N * 4, stream);    // now the fill cursor
    scatter_k<<<(E + 255) / 256, 256, 0, stream>>>(srcp, dstp, dinv, rp, cnt, cw, E);

    // ---- 3 GCN layers ----
    int gemmGrid = (N + 63) / 64;
    int aggGrid  = (int)(((size_t)N * 64 + 255) / 256);

    gemm_k<<<gemmGrid, 256, 0, stream>>>(x, W1, bufT, N);
    agg_k<<<aggGrid, 256, 0, stream>>>(bufT, dinv, rp, cw, b1, bufA, 1, N);

    gemm_k<<<gemmGrid, 256, 0, stream>>>(bufA, W2, bufT, N);
    agg_k<<<aggGrid, 256, 0, stream>>>(bufT, dinv, rp, cw, b2, bufA, 1, N);

    gemm_k<<<gemmGrid, 256, 0, stream>>>(bufA, W3, bufT, N);
    agg_k<<<aggGrid, 256, 0, stream>>>(bufT, dinv, rp, cw, b3, out, 0, N);
}

// Round 8
// 586.829 us; speedup vs baseline: 1.5782x; 1.0095x over previous
//
#include <hip/hip_runtime.h>
#include <hip/hip_fp16.h>

#define DFEAT 128

typedef _Float16 f16x8 __attribute__((ext_vector_type(8)));
typedef _Float16 f16x4 __attribute__((ext_vector_type(4)));
typedef float f32x4 __attribute__((ext_vector_type(4)));

// ---------------- CSR build ----------------

__global__ __launch_bounds__(256) void count_k(const int* __restrict__ dst, int* __restrict__ cnt, int E) {
    int i = (blockIdx.x * 256 + threadIdx.x) * 4;
    if (i + 3 < E) {
        int4 d = *(const int4*)&dst[i];
        atomicAdd(&cnt[d.x], 1);
        atomicAdd(&cnt[d.y], 1);
        atomicAdd(&cnt[d.z], 1);
        atomicAdd(&cnt[d.w], 1);
    } else {
        for (int j = i; j < E; ++j) atomicAdd(&cnt[dst[j]], 1);
    }
}

__global__ __launch_bounds__(256) void dinv_k(const int* __restrict__ cnt, float* __restrict__ dinv, int n) {
    int i = blockIdx.x * 256 + threadIdx.x;
    if (i < n) dinv[i] = rsqrtf((float)(cnt[i] + 1));  // +1 self loop
}

// block-level exclusive scan: 1024 elements/block (256 thr x 4)
__global__ __launch_bounds__(256) void scan1_k(const int* __restrict__ cnt, int* __restrict__ excl,
                                               int* __restrict__ bsums, int n) {
    __shared__ int sd[256];
    int t = threadIdx.x;
    int base = blockIdx.x * 1024 + t * 4;
    int v0 = (base + 0 < n) ? cnt[base + 0] : 0;
    int v1 = (base + 1 < n) ? cnt[base + 1] : 0;
    int v2 = (base + 2 < n) ? cnt[base + 2] : 0;
    int v3 = (base + 3 < n) ? cnt[base + 3] : 0;
    int tsum = v0 + v1 + v2 + v3;
    sd[t] = tsum;
    __syncthreads();
    for (int off = 1; off < 256; off <<= 1) {
        int x = (t >= off) ? sd[t - off] : 0;
        __syncthreads();
        sd[t] += x;
        __syncthreads();
    }
    int incl = sd[t];
    int texcl = incl - tsum;
    if (t == 255) bsums[blockIdx.x] = incl;
    int run = texcl;
    if (base + 0 < n) excl[base + 0] = run; run += v0;
    if (base + 1 < n) excl[base + 1] = run; run += v1;
    if (base + 2 < n) excl[base + 2] = run; run += v2;
    if (base + 3 < n) excl[base + 3] = run;
}

__global__ __launch_bounds__(128) void scan2_k(const int* __restrict__ bsums, int* __restrict__ boffs, int nb) {
    __shared__ int sd[128];
    int t = threadIdx.x;
    int v = (t < nb) ? bsums[t] : 0;
    sd[t] = v;
    __syncthreads();
    for (int off = 1; off < 128; off <<= 1) {
        int x = (t >= off) ? sd[t - off] : 0;
        __syncthreads();
        sd[t] += x;
        __syncthreads();
    }
    boffs[t] = sd[t] - v;  // exclusive
}

__global__ __launch_bounds__(256) void scan3_k(int* __restrict__ rp, const int* __restrict__ boffs, int n, int total) {
    int i = blockIdx.x * 256 + threadIdx.x;
    if (i < n) rp[i] += boffs[i >> 10];
    if (i == 0) rp[n] = total;
}

// one 8B store per edge: {col, wgt} interleaved -> one dirty line per edge, not two
__global__ __launch_bounds__(256) void scatter_k(const int* __restrict__ src, const int* __restrict__ dst,
                                                 const float* __restrict__ dinv, const int* __restrict__ rp,
                                                 int* __restrict__ fill, int2* __restrict__ cw, int E) {
    int i = blockIdx.x * 256 + threadIdx.x;
    if (i >= E) return;
    int d = dst[i], s = src[i];
    int p = rp[d] + atomicAdd(&fill[d], 1);
    float w = dinv[s] * dinv[d];
    int2 rec;
    rec.x = s;
    rec.y = __float_as_int(w);
    cw[p] = rec;
}

// ---------------- GEMM: C[n x 128] = A[n x 128] @ W[128 x 128], MFMA f16, f32 acc ----------------
// Block = 256 thr (4 waves), tile = 64 rows x 128 cols. W packed once/block into
// B-fragment order in LDS; A staged f32->f16 in A-fragment order. 32 MFMAs/wave.
// Fragment maps (verified on gfx950): A: m=lane&15, k=(lane>>4)*8+j;
// B: n=lane&15, k=(lane>>4)*8+j; C/D: col=lane&15, row=(lane>>4)*4+reg.

__global__ __launch_bounds__(256) void gemm_k(const float* __restrict__ A, const float* __restrict__ W,
                                              __half* __restrict__ C, int n) {
    __shared__ _Float16 wl[16384];   // [(ct*4+kc)*64 + lane]*8 + j
    __shared__ _Float16 al[8192];    // [(wv*4+kc)*64 + lane]*8 + j
    const int tid = threadIdx.x;
    const int row0 = blockIdx.x * 64;

    // pack W: f32 row-major [128][128] -> B-frag layout (float4 reads, coalesced)
    for (int e4 = tid; e4 < 4096; e4 += 256) {
        int k  = e4 >> 5;           // 0..127
        int n0 = (e4 & 31) * 4;     // 0..124 (n0%16 in {0,4,8,12} -> same ct for all 4)
        float4 wv4 = *(const float4*)&W[k * DFEAT + n0];
        int kc = k >> 5, quad = (k >> 3) & 3, j = k & 7;
        int ct = n0 >> 4;
        int base = ((ct * 4 + kc) * 64 + quad * 16 + (n0 & 15)) * 8 + j;
        wl[base]      = (_Float16)wv4.x;
        wl[base + 8]  = (_Float16)wv4.y;
        wl[base + 16] = (_Float16)wv4.z;
        wl[base + 24] = (_Float16)wv4.w;
    }
    // stage A tile: 64 rows x 128 k, f32 -> f16, A-frag layout (8B LDS writes)
#pragma unroll
    for (int pass = 0; pass < 8; ++pass) {
        int r  = pass * 8 + (tid >> 5);   // 0..63
        int k4 = (tid & 31) * 4;          // 0..124
        int gr = row0 + r;
        float4 av = make_float4(0.f, 0.f, 0.f, 0.f);
        if (gr < n) av = *(const float4*)&A[(size_t)gr * DFEAT + k4];
        int wv_ = r >> 4, m = r & 15;
        int kc = k4 >> 5, quad = (k4 >> 3) & 3, j0 = k4 & 7;   // j0 in {0,4}
        int dst = ((wv_ * 4 + kc) * 64 + quad * 16 + m) * 8 + j0;
        f16x4 hv = { (_Float16)av.x, (_Float16)av.y, (_Float16)av.z, (_Float16)av.w };
        *(f16x4*)&al[dst] = hv;
    }
    __syncthreads();

    const int wv_  = tid >> 6;   // wave 0..3 -> rows wv_*16..+15
    const int lane = tid & 63;
    f16x8 af[4];
#pragma unroll
    for (int kc = 0; kc < 4; ++kc)
        af[kc] = *(f16x8*)&al[((wv_ * 4 + kc) * 64 + lane) * 8];
    f32x4 acc[8];
#pragma unroll
    for (int ct = 0; ct < 8; ++ct) acc[ct] = (f32x4){0.f, 0.f, 0.f, 0.f};
#pragma unroll
    for (int ct = 0; ct < 8; ++ct) {
#pragma unroll
        for (int kc = 0; kc < 4; ++kc) {
            f16x8 bf = *(f16x8*)&wl[((ct * 4 + kc) * 64 + lane) * 8];
            acc[ct] = __builtin_amdgcn_mfma_f32_16x16x32_f16(af[kc], bf, acc[ct], 0, 0, 0);
        }
    }
    // epilogue: C/D col=lane&15, row=(lane>>4)*4+reg
    const int quad = lane >> 4, cb = lane & 15;
#pragma unroll
    for (int ct = 0; ct < 8; ++ct) {
#pragma unroll
        for (int r = 0; r < 4; ++r) {
            int gr = row0 + wv_ * 16 + quad * 4 + r;
            if (gr < n) C[(size_t)gr * DFEAT + ct * 16 + cb] = __float2half(acc[ct][r]);
        }
    }
}

// ---------------- aggregation: out[i] = dinv[i]^2 * T[i] + sum_e w_e * T[col_e] + b ----------------
// one wave (64 lanes) per node; T is f16, each lane covers 2 features (half2 = 4 B).
// Edge loop unrolled x8: 8 independent gathers in flight per wave.

__global__ __launch_bounds__(256) void agg_k(const __half* __restrict__ T, const float* __restrict__ dinv,
                                             const int* __restrict__ rowptr, const int2* __restrict__ cw,
                                             const float* __restrict__ bias,
                                             float* __restrict__ out, int relu, int n) {
    int wid = (int)((blockIdx.x * (size_t)blockDim.x + threadIdx.x) >> 6);
    int lane = threadIdx.x & 63;
    if (wid >= n) return;
    int fb = lane * 2;
    float di = dinv[wid];
    float2 t0 = __half22float2(*(const __half2*)(T + (size_t)wid * DFEAT + fb));
    float ax = di * di * t0.x;
    float ay = di * di * t0.y;
    int s = rowptr[wid], e = rowptr[wid + 1];
    int p = s;
    int e8 = s + ((e - s) & ~7);
    for (; p < e8; p += 8) {
        int2 r0 = cw[p], r1 = cw[p + 1], r2 = cw[p + 2], r3 = cw[p + 3];
        int2 r4 = cw[p + 4], r5 = cw[p + 5], r6 = cw[p + 6], r7 = cw[p + 7];
        float2 v0 = __half22float2(*(const __half2*)(T + (size_t)r0.x * DFEAT + fb));
        float2 v1 = __half22float2(*(const __half2*)(T + (size_t)r1.x * DFEAT + fb));
        float2 v2 = __half22float2(*(const __half2*)(T + (size_t)r2.x * DFEAT + fb));
        float2 v3 = __half22float2(*(const __half2*)(T + (size_t)r3.x * DFEAT + fb));
        float2 v4 = __half22float2(*(const __half2*)(T + (size_t)r4.x * DFEAT + fb));
        float2 v5 = __half22float2(*(const __half2*)(T + (size_t)r5.x * DFEAT + fb));
        float2 v6 = __half22float2(*(const __half2*)(T + (size_t)r6.x * DFEAT + fb));
        float2 v7 = __half22float2(*(const __half2*)(T + (size_t)r7.x * DFEAT + fb));
        float w0 = __int_as_float(r0.y), w1 = __int_as_float(r1.y);
        float w2 = __int_as_float(r2.y), w3 = __int_as_float(r3.y);
        float w4 = __int_as_float(r4.y), w5 = __int_as_float(r5.y);
        float w6 = __int_as_float(r6.y), w7 = __int_as_float(r7.y);
        ax += w0 * v0.x; ay += w0 * v0.y;
        ax += w1 * v1.x; ay += w1 * v1.y;
        ax += w2 * v2.x; ay += w2 * v2.y;
        ax += w3 * v3.x; ay += w3 * v3.y;
        ax += w4 * v4.x; ay += w4 * v4.y;
        ax += w5 * v5.x; ay += w5 * v5.y;
        ax += w6 * v6.x; ay += w6 * v6.y;
        ax += w7 * v7.x; ay += w7 * v7.y;
    }
    int e4 = s + ((e - s) & ~3);
    if (p < e4) {
        int2 r0 = cw[p], r1 = cw[p + 1], r2 = cw[p + 2], r3 = cw[p + 3];
        float2 v0 = __half22float2(*(const __half2*)(T + (size_t)r0.x * DFEAT + fb));
        float2 v1 = __half22float2(*(const __half2*)(T + (size_t)r1.x * DFEAT + fb));
        float2 v2 = __half22float2(*(const __half2*)(T + (size_t)r2.x * DFEAT + fb));
        float2 v3 = __half22float2(*(const __half2*)(T + (size_t)r3.x * DFEAT + fb));
        float w0 = __int_as_float(r0.y), w1 = __int_as_float(r1.y);
        float w2 = __int_as_float(r2.y), w3 = __int_as_float(r3.y);
        ax += w0 * v0.x; ay += w0 * v0.y;
        ax += w1 * v1.x; ay += w1 * v1.y;
        ax += w2 * v2.x; ay += w2 * v2.y;
        ax += w3 * v3.x; ay += w3 * v3.y;
        p += 4;
    }
    for (; p < e; ++p) {
        int2 r = cw[p];
        float w = __int_as_float(r.y);
        float2 tv = __half22float2(*(const __half2*)(T + (size_t)r.x * DFEAT + fb));
        ax += w * tv.x;
        ay += w * tv.y;
    }
    ax += bias[fb];
    ay += bias[fb + 1];
    if (relu) { ax = fmaxf(ax, 0.f); ay = fmaxf(ay, 0.f); }
    float2 o; o.x = ax; o.y = ay;
    *(float2*)(out + (size_t)wid * DFEAT + fb) = o;
}

// ---------------- launch ----------------

extern "C" void kernel_launch(void* const* d_in, const int* in_sizes, int n_in,
                              void* d_out, int out_size, void* d_ws, size_t ws_size,
                              hipStream_t stream) {
    const float* x  = (const float*)d_in[0];
    const int*   ei = (const int*)d_in[1];
    const float* W1 = (const float*)d_in[2];
    const float* b1 = (const float*)d_in[3];
    const float* W2 = (const float*)d_in[4];
    const float* b2 = (const float*)d_in[5];
    const float* W3 = (const float*)d_in[6];
    const float* b3 = (const float*)d_in[7];
    float* out = (float*)d_out;

    const int N = in_sizes[0] / DFEAT;
    const int E = in_sizes[1] / 2;
    const int* srcp = ei;
    const int* dstp = ei + E;

    size_t off = 0;
    auto alloc = [&](size_t bytes) -> void* {
        void* p = (char*)d_ws + off;
        off += (bytes + 255) & ~(size_t)255;
        return p;
    };
    int*    cnt   = (int*)alloc((size_t)N * 4);        // degree counts, reused as fill cursor
    int*    rp    = (int*)alloc((size_t)(N + 1) * 4);  // CSR row_ptr
    int*    bsums = (int*)alloc(1024);
    int*    boffs = (int*)alloc(1024);
    float*  dinv  = (float*)alloc((size_t)N * 4);
    int2*   cw    = (int2*)alloc((size_t)E * 8);       // interleaved {col, wgt}
    float*  bufA  = (float*)alloc((size_t)N * DFEAT * 4);   // agg output (f32, GEMM input)
    __half* bufT  = (__half*)alloc((size_t)N * DFEAT * 2);  // GEMM output (f16, gather src)

    // ---- CSR build (by dst) ----
    hipMemsetAsync(cnt, 0, (size_t)N * 4, stream);
    count_k<<<(E / 4 + 255) / 256, 256, 0, stream>>>(dstp, cnt, E);
    dinv_k<<<(N + 255) / 256, 256, 0, stream>>>(cnt, dinv, N);
    int NB = (N + 1023) / 1024;   // 98 for N=100000, must be <=128
    scan1_k<<<NB, 256, 0, stream>>>(cnt, rp, bsums, N);
    scan2_k<<<1, 128, 0, stream>>>(bsums, boffs, NB);
    scan3_k<<<(N + 255) / 256, 256, 0, stream>>>(rp, boffs, N, E);
    hipMemsetAsync(cnt, 0, (size_t)N * 4, stream);    // now the fill cursor
    scatter_k<<<(E + 255) / 256, 256, 0, stream>>>(srcp, dstp, dinv, rp, cnt, cw, E);

    // ---- 3 GCN layers ----
    int gemmGrid = (N + 63) / 64;
    int aggGrid  = (int)(((size_t)N * 64 + 255) / 256);

    gemm_k<<<gemmGrid, 256, 0, stream>>>(x, W1, bufT, N);
    agg_k<<<aggGrid, 256, 0, stream>>>(bufT, dinv, rp, cw, b1, bufA, 1, N);

    gemm_k<<<gemmGrid, 256, 0, stream>>>(bufA, W2, bufT, N);
    agg_k<<<aggGrid, 256, 0, stream>>>(bufT, dinv, rp, cw, b2, bufA, 1, N);

    gemm_k<<<gemmGrid, 256, 0, stream>>>(bufA, W3, bufT, N);
    agg_k<<<aggGrid, 256, 0, stream>>>(bufT, dinv, rp, cw, b3, out, 0, N);
}